// Round 6
// baseline (184.166 us; speedup 1.0000x reference)
//
#include <hip/hip_runtime.h>
#include <hip/hip_cooperative_groups.h>
#include <math.h>

namespace cg = cooperative_groups;

typedef short short8 __attribute__((ext_vector_type(8)));
typedef float f32x4 __attribute__((ext_vector_type(4)));
typedef unsigned int u32x4 __attribute__((ext_vector_type(4)));
typedef unsigned int u32x2 __attribute__((ext_vector_type(2)));

namespace {
constexpr int kNS = 16;
constexpr int kNV = 4;
constexpr int kNG = 50;
constexpr int kHID = 64;
constexpr int kAttr = 28;                 // NS + 3*NV
constexpr int kWNUM = 400;
constexpr float kStep = 5.0f / 49.0f;
constexpr float kCoeff = -0.5f / (kStep * kStep);
constexpr float kSqrt3 = 1.7320508075688772f;
constexpr float kInvSqrt3 = 0.57735026918962576f;
constexpr float kInvSqrt20 = 0.22360679774997896f;
// Row = 208 B (13 granules): 52 words == 20 mod 32 -> 16 rows spread over 8
// bank-offset classes (2 lanes/bank = free). No XOR swizzle (r3 lesson: XOR
// escapes a non-power-of-2 row).
constexpr int kRowB = 208;
constexpr int kAuxB = 48;                 // aux row: 20 bf16 o0 (+pad)
constexpr int kImg1Bytes = 96 * 64 * 2;   // 12288
constexpr int kImg2Bytes = 64 * 400 * 2;  // 51200
constexpr int kSortBlocks = 64;           // coop kernel: 64 blocks, co-resident
}  // namespace

// Manual round-to-nearest-even bf16. Round 5 lesson: __float2bfloat16 /
// __float22bfloat162_rn on this toolchain inflate error ~1.5x (truncation);
// manual RNE passed at absmax 0.068 vs threshold 0.101.
__device__ __forceinline__ unsigned short f2bf(float x) {
  unsigned u = __float_as_uint(x);
  return (unsigned short)((u + 0x7FFFu + ((u >> 16) & 1u)) >> 16);
}
__device__ __forceinline__ unsigned pack2(float lo, float hi) {
  return (unsigned)f2bf(lo) | ((unsigned)f2bf(hi) << 16);
}
__device__ __forceinline__ float bf2f(unsigned short v) {
  return __uint_as_float(((unsigned)v) << 16);
}

// ---------- cooperative pre-pass: zero + weight prep -> hist -> scan -> scatter
// One dispatch replaces {memset, memset, prep, hist, scan, scatter}: each
// enqueued op costs ~9us fixed in the replay (r1/r2/r4 gap analysis), so
// dispatch count is the lever.
__global__ __launch_bounds__(256) void coop_sort_kernel(
    const float* __restrict__ W1, const float* __restrict__ W2,
    unsigned short* __restrict__ img1, unsigned short* __restrict__ img2,
    const int* __restrict__ edge_index, int* __restrict__ cnt,
    int* __restrict__ cur, int* __restrict__ ssrc, int* __restrict__ sdst,
    float* __restrict__ agg, int aggN4, int N, int E) {
  cg::grid_group grid = cg::this_grid();
  const int gtid = blockIdx.x * 256 + threadIdx.x;
  const int gsz = gridDim.x * 256;

  // ---- phase 0: zero agg (d_out) + cnt; pack W1/W2 bf16 fragment images ----
  f32x4* agg4 = (f32x4*)agg;
  for (int i = gtid; i < aggN4; i += gsz) agg4[i] = f32x4{0.f, 0.f, 0.f, 0.f};
  for (int i = gtid; i < N; i += gsz) cnt[i] = 0;
  // img layout: element (k, n) at byte ((k>>3)*W + n)*16 + 2*(k&7)
  for (int i = gtid; i < 96 * 64 + 64 * 400; i += gsz) {
    if (i < 96 * 64) {
      const int m = i >> 6, n = i & 63;
      float v = 0.0f;
      if (m < 50) v = W1[m * 64 + n];                        // gaussian rows
      else if (m >= 56 && m < 88) v = W1[(m - 6) * 64 + n];  // ss, ds rows
      img1[((m >> 3) * 64 + n) * 8 + (m & 7)] = f2bf(v);
    } else {
      const int j = i - 96 * 64;
      const int m = j / 400, n = j % 400;
      img2[((m >> 3) * 400 + n) * 8 + (m & 7)] = f2bf(W2[m * 400 + n]);
    }
  }
  grid.sync();

  // ---- phase 1: histogram of dst ----
  for (int e = gtid; e < E; e += gsz) atomicAdd(cnt + edge_index[E + e], 1);
  grid.sync();

  // ---- phase 2: exclusive scan (block 0; others idle at the sync) ----
  if (blockIdx.x == 0) {
    __shared__ int sums[256];
    const int tid = threadIdx.x;
    const int chunk = (N + 255) / 256;
    const int base = tid * chunk;
    int s = 0;
    for (int j = 0; j < chunk; j++) {
      const int i = base + j;
      if (i < N) s += cnt[i];
    }
    sums[tid] = s;
    __syncthreads();
    for (int d = 1; d < 256; d <<= 1) {
      const int y = (tid >= d) ? sums[tid - d] : 0;
      __syncthreads();
      sums[tid] += y;
      __syncthreads();
    }
    int run = sums[tid] - s;
    for (int j = 0; j < chunk; j++) {
      const int i = base + j;
      if (i < N) { cur[i] = run; run += cnt[i]; }
    }
  }
  grid.sync();

  // ---- phase 3: scatter into dst-sorted order ----
  for (int e = gtid; e < E; e += gsz) {
    const int s = edge_index[e];
    const int d = edge_index[E + e];
    const int p = atomicAdd(cur + d, 1);
    ssrc[p] = s;
    sdst[p] = d;
  }
}

// ---------- main MFMA edge kernel ----------
// Per wave: 64 edges (4 groups of 16). All LDS traffic is wave-local.
// ub row (208B): chunks 0..11 = ef(96 bf16); then chunks 0..7 overwritten by
// h(64 bf16), chunks 8..11 by sh/v1 f32 stash (after eff hoist); finally
// chunks 0..6 overwritten by msg(28 f32).
__global__ __launch_bounds__(256, 2) void tfn_mfma_kernel(
    const float* __restrict__ node_attr, const float* __restrict__ pos,
    const float* __restrict__ b1, const float* __restrict__ b2,
    const char* __restrict__ img1, const char* __restrict__ img2,
    const int* __restrict__ ssrc, const int* __restrict__ sdst,
    float* __restrict__ agg, int E) {
  __shared__ __align__(16) char ub[256 * kRowB];   // 53248 B
  __shared__ __align__(16) char ax[256 * kAuxB];   // 12288 B

  const int tid = threadIdx.x;
  const int t = blockIdx.x * 256 + tid;
  const int lane = tid & 63;
  const int wv = tid >> 6;
  const int lc = lane & 15, lq = lane >> 4;

  const bool valid = (t < E);
  int src = 0, dstv = -1;
  if (valid) { src = ssrc[t]; dstv = sdst[t]; }
  const int dn = valid ? dstv : 0;

  // ---- geometry ----
  const float psx = pos[src * 3 + 0], psy = pos[src * 3 + 1], psz = pos[src * 3 + 2];
  const float pdx = pos[dn * 3 + 0], pdy = pos[dn * 3 + 1], pdz = pos[dn * 3 + 2];
  const float vx = pdx - psx, vy = pdy - psy, vz = pdz - psz;
  const float dist = sqrtf(vx * vx + vy * vy + vz * vz);
  const float rinv = 1.0f / fmaxf(dist, 1e-8f);
  const float sh0 = kSqrt3 * (vy * rinv);
  const float sh1 = kSqrt3 * (vz * rinv);
  const float sh2 = kSqrt3 * (vx * rinv);

  const float* nas = node_attr + (size_t)src * kAttr;
  const float* nad = node_attr + (size_t)dn * kAttr;
  const float4 sa = *(const float4*)(nas + 0);
  const float4 sb = *(const float4*)(nas + 4);
  const float4 sc4 = *(const float4*)(nas + 8);
  const float4 sd4 = *(const float4*)(nas + 12);
  const float4 va = *(const float4*)(nas + 16);
  const float4 vb = *(const float4*)(nas + 20);
  const float4 vc = *(const float4*)(nas + 24);
  const float4 da = *(const float4*)(nad + 0);
  const float4 db = *(const float4*)(nad + 4);
  const float4 dc4 = *(const float4*)(nad + 8);
  const float4 dd4 = *(const float4*)(nad + 12);

  char* myrow = ub + tid * kRowB;

  // ---- write ef row (96 bf16): [gauss50 | 0x6 | ss16 | ds16 | 0x8] ----
  {
    const float base = dist + 1e-6f;
#pragma unroll
    for (int c = 0; c < 6; ++c) {
      unsigned p[4];
#pragma unroll
      for (int u = 0; u < 4; ++u) {
        const int k = c * 8 + u * 2;
        const float d0 = base - (float)k * kStep;
        const float d1 = base - (float)(k + 1) * kStep;
        p[u] = pack2(__expf(kCoeff * d0 * d0), __expf(kCoeff * d1 * d1));
      }
      *(u32x4*)(myrow + c * 16) = u32x4{p[0], p[1], p[2], p[3]};
    }
    const float d0 = base - 48.0f * kStep, d1 = base - 49.0f * kStep;
    *(u32x4*)(myrow + 6 * 16) =
        u32x4{pack2(__expf(kCoeff * d0 * d0), __expf(kCoeff * d1 * d1)), 0u, 0u, 0u};
    *(u32x4*)(myrow + 7 * 16) =
        u32x4{pack2(sa.x, sa.y), pack2(sa.z, sa.w), pack2(sb.x, sb.y), pack2(sb.z, sb.w)};
    *(u32x4*)(myrow + 8 * 16) =
        u32x4{pack2(sc4.x, sc4.y), pack2(sc4.z, sc4.w), pack2(sd4.x, sd4.y), pack2(sd4.z, sd4.w)};
    *(u32x4*)(myrow + 9 * 16) =
        u32x4{pack2(da.x, da.y), pack2(da.z, da.w), pack2(db.x, db.y), pack2(db.z, db.w)};
    *(u32x4*)(myrow + 10 * 16) =
        u32x4{pack2(dc4.x, dc4.y), pack2(dc4.z, dc4.w), pack2(dd4.x, dd4.y), pack2(dd4.z, dd4.w)};
    *(u32x4*)(myrow + 11 * 16) = u32x4{0u, 0u, 0u, 0u};
  }

  // ---- aux row: o0[20] as bf16 ----
  const float v1f[12] = {va.x, va.y, va.z, va.w, vb.x, vb.y, vb.z, vb.w,
                         vc.x, vc.y, vc.z, vc.w};
  {
    const float t0 = (v1f[0] * sh0 + v1f[1] * sh1 + v1f[2] * sh2) * kInvSqrt3;
    const float t1 = (v1f[3] * sh0 + v1f[4] * sh1 + v1f[5] * sh2) * kInvSqrt3;
    const float t2 = (v1f[6] * sh0 + v1f[7] * sh1 + v1f[8] * sh2) * kInvSqrt3;
    const float t3 = (v1f[9] * sh0 + v1f[10] * sh1 + v1f[11] * sh2) * kInvSqrt3;
    char* myax = ax + tid * kAuxB;
    *(u32x4*)(myax + 0) = u32x4{pack2(sa.x, sa.y), pack2(sa.z, sa.w),
                                pack2(sb.x, sb.y), pack2(sb.z, sb.w)};
    *(u32x4*)(myax + 16) = u32x4{pack2(sc4.x, sc4.y), pack2(sc4.z, sc4.w),
                                 pack2(sd4.x, sd4.y), pack2(sd4.z, sd4.w)};
    *(u32x2*)(myax + 32) = u32x2{pack2(t0, t1), pack2(t2, t3)};
  }

  // ---- hoist ef fragments (B-operand: lane holds ef[e=g*16+lc][k=(ks*4+lq)*8+j]) ----
  short8 eff[4][3];
#pragma unroll
  for (int g = 0; g < 4; ++g) {
    const char* rp = ub + (wv * 64 + g * 16 + lc) * kRowB;
#pragma unroll
    for (int ks = 0; ks < 3; ++ks)
      eff[g][ks] = *(const short8*)(rp + (ks * 4 + lq) * 16);
  }

  // ---- stash sh/v1 as f32 into chunks 8..11 (ef chunks 8..11 now dead) ----
  *(f32x4*)(myrow + 8 * 16) = f32x4{sh0, sh1, sh2, v1f[0]};
  *(f32x4*)(myrow + 9 * 16) = f32x4{v1f[1], v1f[2], v1f[3], v1f[4]};
  *(f32x4*)(myrow + 10 * 16) = f32x4{v1f[5], v1f[6], v1f[7], v1f[8]};
  *(f32x4*)(myrow + 11 * 16) = f32x4{v1f[9], v1f[10], v1f[11], 0.0f};

  // ---- MFMA-1: h[n][e] = relu(b1[n] + sum_k W1p[k][n] ef[e][k]) ----
#pragma unroll
  for (int nt = 0; nt < 4; ++nt) {
    const short8 a0 = *(const short8*)(img1 + ((0 + lq) * 64 + nt * 16 + lc) * 16);
    const short8 a1 = *(const short8*)(img1 + ((4 + lq) * 64 + nt * 16 + lc) * 16);
    const short8 a2 = *(const short8*)(img1 + ((8 + lq) * 64 + nt * 16 + lc) * 16);
    const f32x4 bias = *(const f32x4*)(b1 + nt * 16 + lq * 4);
#pragma unroll
    for (int g = 0; g < 4; ++g) {
      f32x4 acc = bias;
      acc = __builtin_amdgcn_mfma_f32_16x16x32_bf16(a0, eff[g][0], acc, 0, 0, 0);
      acc = __builtin_amdgcn_mfma_f32_16x16x32_bf16(a1, eff[g][1], acc, 0, 0, 0);
      acc = __builtin_amdgcn_mfma_f32_16x16x32_bf16(a2, eff[g][2], acc, 0, 0, 0);
      const unsigned p0 = pack2(fmaxf(acc[0], 0.0f), fmaxf(acc[1], 0.0f));
      const unsigned p1 = pack2(fmaxf(acc[2], 0.0f), fmaxf(acc[3], 0.0f));
      const int row = wv * 64 + g * 16 + lc;
      // n = nt*16 + lq*4 + r -> byte 2n = nt*32 + lq*8
      *(u32x2*)(ub + row * kRowB + nt * 32 + lq * 8) = u32x2{p0, p1};
    }
  }

  // ---- load h fragments (B-operand: lane holds h[k][e=g*16+lc]) ----
  short8 hf[4][2];
#pragma unroll
  for (int g = 0; g < 4; ++g) {
    const char* rp = ub + (wv * 64 + g * 16 + lc) * kRowB;
    hf[g][0] = *(const short8*)(rp + (0 + lq) * 16);
    hf[g][1] = *(const short8*)(rp + (4 + lq) * 16);
  }

  // ---- hoist per-edge sh / v1 (lane owns edge lc of each group) ----
  float shv[4][3], v1h[4][3];
#pragma unroll
  for (int g = 0; g < 4; ++g) {
    const char* rp = ub + (wv * 64 + g * 16 + lc) * kRowB;
#pragma unroll
    for (int c = 0; c < 3; ++c) {
      shv[g][c] = *(const float*)(rp + 128 + 4 * c);
      v1h[g][c] = *(const float*)(rp + 140 + 12 * lq + 4 * c);
    }
  }

  // ---- MFMA-2 + fused contraction. D[n][e]: lane owns edge lc, n = 16nt+4lq+r ----
  float macc0[4][4] = {};
  float macc1[4][4][3] = {};

#pragma unroll 5
  for (int nt = 0; nt < 20; ++nt) {
    const short8 w0 = *(const short8*)(img2 + ((0 + lq) * 400 + nt * 16 + lc) * 16);
    const short8 w1 = *(const short8*)(img2 + ((4 + lq) * 400 + nt * 16 + lc) * 16);
    const f32x4 bias = *(const f32x4*)(b2 + nt * 16 + lq * 4);
#pragma unroll
    for (int g = 0; g < 4; ++g) {
      f32x4 acc = bias;
      acc = __builtin_amdgcn_mfma_f32_16x16x32_bf16(w0, hf[g][0], acc, 0, 0, 0);
      acc = __builtin_amdgcn_mfma_f32_16x16x32_bf16(w1, hf[g][1], acc, 0, 0, 0);
      const int row = wv * 64 + g * 16 + lc;
      const float o0v = bf2f(*(const unsigned short*)(ax + row * kAuxB + 2 * nt));
#pragma unroll
      for (int r = 0; r < 4; ++r) macc0[g][r] = fmaf(o0v, acc[r], macc0[g][r]);
    }
  }
#pragma unroll
  for (int nt = 20; nt < 24; ++nt) {
    const short8 w0 = *(const short8*)(img2 + ((0 + lq) * 400 + nt * 16 + lc) * 16);
    const short8 w1 = *(const short8*)(img2 + ((4 + lq) * 400 + nt * 16 + lc) * 16);
    const f32x4 bias = *(const f32x4*)(b2 + nt * 16 + lq * 4);
#pragma unroll
    for (int g = 0; g < 4; ++g) {
      f32x4 acc = bias;
      acc = __builtin_amdgcn_mfma_f32_16x16x32_bf16(w0, hf[g][0], acc, 0, 0, 0);
      acc = __builtin_amdgcn_mfma_f32_16x16x32_bf16(w1, hf[g][1], acc, 0, 0, 0);
      const int row = wv * 64 + g * 16 + lc;
      // i = 4*(nt-20) + lq, o = r; o1[i] = ss[i] * sh
      const float ssv =
          bf2f(*(const unsigned short*)(ax + row * kAuxB + 2 * (4 * (nt - 20) + lq)));
      float pc[3];
#pragma unroll
      for (int c = 0; c < 3; ++c) pc[c] = ssv * shv[g][c];
#pragma unroll
      for (int r = 0; r < 4; ++r)
#pragma unroll
        for (int c = 0; c < 3; ++c)
          macc1[g][r][c] = fmaf(pc[c], acc[r], macc1[g][r][c]);
    }
  }
  {  // nt = 24: i = 16 + lq, o1 row = in_1o
    const int nt = 24;
    const short8 w0 = *(const short8*)(img2 + ((0 + lq) * 400 + nt * 16 + lc) * 16);
    const short8 w1 = *(const short8*)(img2 + ((4 + lq) * 400 + nt * 16 + lc) * 16);
    const f32x4 bias = *(const f32x4*)(b2 + nt * 16 + lq * 4);
#pragma unroll
    for (int g = 0; g < 4; ++g) {
      f32x4 acc = bias;
      acc = __builtin_amdgcn_mfma_f32_16x16x32_bf16(w0, hf[g][0], acc, 0, 0, 0);
      acc = __builtin_amdgcn_mfma_f32_16x16x32_bf16(w1, hf[g][1], acc, 0, 0, 0);
#pragma unroll
      for (int r = 0; r < 4; ++r)
#pragma unroll
        for (int c = 0; c < 3; ++c)
          macc1[g][r][c] = fmaf(v1h[g][c], acc[r], macc1[g][r][c]);
    }
  }

  // ---- finish msg1 (reduce i-partition across lq groups), scale, write msg rows ----
#pragma unroll
  for (int g = 0; g < 4; ++g)
#pragma unroll
    for (int r = 0; r < 4; ++r)
#pragma unroll
      for (int c = 0; c < 3; ++c) {
        float x = macc1[g][r][c];
        x += __shfl_xor(x, 16);
        x += __shfl_xor(x, 32);
        macc1[g][r][c] = x * kInvSqrt20;
      }
#pragma unroll
  for (int g = 0; g < 4; ++g) {
    char* rp = ub + (wv * 64 + g * 16 + lc) * kRowB;
    *(f32x4*)(rp + lq * 16) =
        f32x4{macc0[g][0] * kInvSqrt20, macc0[g][1] * kInvSqrt20,
              macc0[g][2] * kInvSqrt20, macc0[g][3] * kInvSqrt20};
    f32x4 m1;
    if (lq == 1)
      m1 = f32x4{macc1[g][0][0], macc1[g][0][1], macc1[g][0][2], macc1[g][1][0]};
    else if (lq == 2)
      m1 = f32x4{macc1[g][1][1], macc1[g][1][2], macc1[g][2][0], macc1[g][2][1]};
    else
      m1 = f32x4{macc1[g][2][2], macc1[g][3][0], macc1[g][3][1], macc1[g][3][2]};
    if (lq != 0) *(f32x4*)(rp + 48 + lq * 16) = m1;
  }

  // ---- read back own msg, segmented wave reduction, one atomic per segment head ----
  float msg[28];
  {
    const char* rp = ub + tid * kRowB;
#pragma unroll
    for (int c = 0; c < 7; ++c) {
      const f32x4 v = *(const f32x4*)(rp + c * 16);
      msg[c * 4 + 0] = v[0];
      msg[c * 4 + 1] = v[1];
      msg[c * 4 + 2] = v[2];
      msg[c * 4 + 3] = v[3];
    }
  }
#pragma unroll
  for (int d = 1; d < 64; d <<= 1) {
    const int od = __shfl_down(dstv, d);
    const bool same = (lane + d < 64) && (od == dstv);
#pragma unroll
    for (int j = 0; j < 28; j++) {
      const float ov = __shfl_down(msg[j], d);
      if (same) msg[j] += ov;
    }
  }
  const int pd = __shfl_up(dstv, 1);
  if ((lane == 0 || pd != dstv) && dstv >= 0) {
    float* ap = agg + (size_t)dstv * kAttr;
#pragma unroll
    for (int j = 0; j < 28; j++) atomicAdd(ap + j, msg[j]);
  }
}

__global__ __launch_bounds__(256) void tfn_finalize_kernel(
    const float* __restrict__ node_attr, const int* __restrict__ cnt,
    float* __restrict__ out, int total) {
  const int i = blockIdx.x * blockDim.x + threadIdx.x;
  if (i >= total) return;
  const int n = i / kAttr;
  const float c = fmaxf((float)cnt[n], 1.0f);
  out[i] = node_attr[i] + out[i] / c;
}

// ---------- fallback aux kernels (only used if ws is too small) ----------
__global__ __launch_bounds__(256) void hist_kernel(
    const int* __restrict__ edge_index, int* __restrict__ cnt, int E) {
  const int e = blockIdx.x * blockDim.x + threadIdx.x;
  if (e >= E) return;
  atomicAdd(cnt + edge_index[E + e], 1);
}
__global__ __launch_bounds__(256) void prep_kernel(
    const float* __restrict__ W1, const float* __restrict__ W2,
    unsigned short* __restrict__ img1, unsigned short* __restrict__ img2) {
  const int i = blockIdx.x * 256 + threadIdx.x;
  if (i < 96 * 64) {
    const int m = i >> 6, n = i & 63;
    float v = 0.0f;
    if (m < 50) v = W1[m * 64 + n];
    else if (m >= 56 && m < 88) v = W1[(m - 6) * 64 + n];
    img1[((m >> 3) * 64 + n) * 8 + (m & 7)] = f2bf(v);
  } else if (i < 96 * 64 + 64 * 400) {
    const int j = i - 96 * 64;
    const int m = j / 400, n = j % 400;
    img2[((m >> 3) * 400 + n) * 8 + (m & 7)] = f2bf(W2[m * 400 + n]);
  }
}

extern "C" void kernel_launch(void* const* d_in, const int* in_sizes, int n_in,
                              void* d_out, int out_size, void* d_ws, size_t ws_size,
                              hipStream_t stream) {
  const float* node_attr = (const float*)d_in[0];
  const float* pos = (const float*)d_in[1];
  const float* W1 = (const float*)d_in[2];
  const float* b1 = (const float*)d_in[3];
  const float* W2 = (const float*)d_in[4];
  const float* b2 = (const float*)d_in[5];
  const int* edge_index = (const int*)d_in[6];

  const int N = in_sizes[0] / kAttr;
  const int E = in_sizes[6] / 2;

  // ws layout: [img1 12288B][img2 51200B][cnt N][cur N][ssrc E][sdst E]
  char* wsc = (char*)d_ws;
  unsigned short* img1 = (unsigned short*)wsc;
  unsigned short* img2 = (unsigned short*)(wsc + kImg1Bytes);
  int* cnt = (int*)(wsc + kImg1Bytes + kImg2Bytes);
  int* cur = cnt + N;
  int* ssrc = cur + N;
  int* sdst = ssrc + E;
  const size_t need_full =
      (size_t)kImg1Bytes + kImg2Bytes + (size_t)(2 * N + 2 * E) * sizeof(int);
  const bool sorted = (ws_size >= need_full);

  float* agg = (float*)d_out;
  const int eblocks = (E + 255) / 256;
  const int total = N * kAttr;

  if (sorted) {
    // 3 dispatches total: coop pre-pass, main, finalize.
    int aggN4 = out_size / 4;
    void* args[] = {(void*)&W1,  (void*)&W2,  (void*)&img1, (void*)&img2,
                    (void*)&edge_index, (void*)&cnt, (void*)&cur,
                    (void*)&ssrc, (void*)&sdst, (void*)&agg,
                    (void*)&aggN4, (void*)&N, (void*)&E};
    hipLaunchCooperativeKernel((const void*)coop_sort_kernel, dim3(kSortBlocks),
                               dim3(256), args, 0, stream);
    tfn_mfma_kernel<<<eblocks, 256, 0, stream>>>(
        node_attr, pos, b1, b2, (const char*)img1, (const char*)img2,
        ssrc, sdst, agg, E);
  } else {
    // fallback: unsorted path (more atomics, more dispatches; correctness only)
    hipMemsetAsync(d_out, 0, (size_t)out_size * sizeof(float), stream);
    hipMemsetAsync(cnt, 0, (size_t)N * sizeof(int), stream);
    prep_kernel<<<(96 * 64 + 64 * 400 + 255) / 256, 256, 0, stream>>>(W1, W2, img1, img2);
    hist_kernel<<<eblocks, 256, 0, stream>>>(edge_index, cnt, E);
    tfn_mfma_kernel<<<eblocks, 256, 0, stream>>>(
        node_attr, pos, b1, b2, (const char*)img1, (const char*)img2,
        edge_index, edge_index + E, agg, E);
  }

  tfn_finalize_kernel<<<(total + 255) / 256, 256, 0, stream>>>(
      node_attr, cnt, (float*)d_out, total);
}